// Round 7
// baseline (155.619 us; speedup 1.0000x reference)
//
#include <hip/hip_runtime.h>

#define N_ 16
#define T_ 1024
#define E_ 1024
#define H_ 256
#define MAXOUT 4096
#define M_ (N_ * T_)          // 16384 rows
#define NJ 768                // 3*H_ GEMM output cols
#define NJ16 48               // NJ/16

typedef _Float16 half_t;
typedef __attribute__((ext_vector_type(8))) _Float16 f16x8;
typedef __attribute__((ext_vector_type(4))) _Float16 f16x4;
typedef __attribute__((ext_vector_type(4))) float f32x4;

// ---------------- d_out scratch layout (bytes) ----------------
// upsample (last kernel) rewrites the entire main output region.
constexpr size_t Y1_OFF  = 0;                       // 16384*768*2  = 25165824
constexpr size_t Y2_OFF  = 25165824;                // + 25165824
constexpr size_t A2P_OFF = 50331648;                // 16384*256*2  = 8388608 -> ends 58720256

// ---------------- d_ws layout (bytes) ----------------
constexpr size_t B1P_OFF  = 0;            // 786432*2 = 1572864
constexpr size_t B2P_OFF  = 1572864;      // 196608*2 = 393216
constexpr size_t DUR_OFF  = 1966080;      // 16384*4
constexpr size_t CUM_OFF  = 2031616;      // 16384*4

// mask decode, dtype-robust. padding_mask[0][1] is guaranteed true (lens>=512):
// bool-byte storage -> raw[1]==1; int32/float32 -> raw[1]==0, read 4-byte words.
__device__ __forceinline__ float mask_at(const unsigned char* __restrict__ raw, int i) {
    if (raw[1] == 1) return raw[i] ? 1.0f : 0.0f;
    return reinterpret_cast<const int*>(raw)[i] ? 1.0f : 0.0f;
}

__device__ __forceinline__ void gload_lds16(const void* g, void* l) {
    __builtin_amdgcn_global_load_lds(
        (const __attribute__((address_space(1))) unsigned int*)g,
        (__attribute__((address_space(3))) unsigned int*)l, 16, 0, 0);
}

// ---------------- weight prep: w[h][e][k] -> B[e][j=k*256+h] blocked [bk][bj=48][64][8] f16 ----
__global__ __launch_bounds__(256) void prep_w_kernel(
    const float* __restrict__ w1, const float* __restrict__ w2,
    half_t* __restrict__ B1p, half_t* __restrict__ B2p) {
    const int bid = blockIdx.x;            // 0..383 W1 | 384..479 W2
    const bool isW1 = (bid < 384);
    const int c = (isW1 ? bid : bid - 384) * 256 + threadIdx.x;
    const int EIN = isW1 ? E_ : H_;
    const float* w = isW1 ? w1 : w2;
    half_t* Bp = isW1 ? B1p : B2p;
    const int l = c & 63;
    const int t = c >> 6;
    const int bj = t % NJ16;
    const int bk = t / NJ16;
    const int j = bj * 16 + (l & 15);
    const int k = j >> 8;           // 0..2
    const int h = j & 255;
    const int e0 = bk * 32 + ((l >> 4) * 8);
    f16x8 h8;
#pragma unroll
    for (int jj = 0; jj < 8; ++jj)
        h8[jj] = (half_t)w[((size_t)h * EIN + e0 + jj) * 3 + k];
    *reinterpret_cast<f16x8*>(Bp + (size_t)c * 8) = h8;
}

// ---------------- fused conv1 GEMM: A from f32 seqs (mask+cvt in-kernel) ----------------
// Y1[M][768](f16) = (seqs*mask)[M][1024] * B1[1024][768]
// A: 4x f32x4 global loads issued at TOP of body (latency hidden under 48-MFMA
//    cluster), cvt+mask+ds_write AFTER MFMA, single barrier per K-step.
// B: global_load_lds (unchanged from round 6).
// 1-D grid 768 blocks, XCD-chunked + j-inner (A-panel sharers same-XCD-adjacent).
__global__ __launch_bounds__(256, 4) void gemm1_fused_kernel(
    const float* __restrict__ seqs, const unsigned char* __restrict__ mraw,
    const half_t* __restrict__ Bp, half_t* __restrict__ Y) {
    constexpr int NBK = 32;
    __shared__ __align__(16) half_t lds[2][2][4096];   // [buf][A,B][128x32 tile] = 32 KB
    const int tid = threadIdx.x;
    const int l = tid & 63;
    const int wv = tid >> 6;
    const int wr = wv >> 1, wc = wv & 1;

    const int d = blockIdx.x;                  // 0..767
    const int work = (d & 7) * 96 + (d >> 3);  // XCD-chunked
    const int bjIdx = work % 6;                // j-inner
    const int bmIdx = work / 6;
    const int bm0 = bmIdx * 8;
    const int bj0 = bjIdx * 8;

    f32x4 acc[4][4] = {};
    f32x4 rA[4];

    // A staging geometry: thread stages chunks q=tid (rows blk*16+(tid&15)) and
    // q=tid+256 (row +64); 8 f32 each at kgroup (l>>4)*8.
    const int r1 = (bm0 + (tid >> 6)) * 16 + (tid & 15);
    const int r2 = r1 + 64;
    const int cbase = ((tid & 63) >> 4) * 8;
    const float mv1 = mask_at(mraw, r1);
    const float mv2 = mask_at(mraw, r2);
    const float* pA1 = seqs + (size_t)r1 * E_ + cbase;
    const float* pA2 = seqs + (size_t)r2 * E_ + cbase;

    auto issueA = [&](int kb) {   // f32 loads -> regs (issued early)
        rA[0] = *reinterpret_cast<const f32x4*>(pA1 + kb * 32);
        rA[1] = *reinterpret_cast<const f32x4*>(pA1 + kb * 32 + 4);
        rA[2] = *reinterpret_cast<const f32x4*>(pA2 + kb * 32);
        rA[3] = *reinterpret_cast<const f32x4*>(pA2 + kb * 32 + 4);
    };
    auto writeA = [&](int buf) {  // mask + cvt + ds_write (after MFMA)
        f16x8 h1, h2;
#pragma unroll
        for (int j = 0; j < 4; ++j) {
            h1[j]     = (half_t)(rA[0][j] * mv1);
            h1[4 + j] = (half_t)(rA[1][j] * mv1);
            h2[j]     = (half_t)(rA[2][j] * mv2);
            h2[4 + j] = (half_t)(rA[3][j] * mv2);
        }
        *reinterpret_cast<f16x8*>(&lds[buf][0][(size_t)tid * 8]) = h1;
        *reinterpret_cast<f16x8*>(&lds[buf][0][(size_t)(tid + 256) * 8]) = h2;
    };
    auto stageB = [&](int kb, int buf) {
#pragma unroll
        for (int s = 0; s < 2; ++s) {
            const int q = tid + 256 * s;
            const int blk = q >> 6;
            const int ql = q & 63;
            gload_lds16(Bp + (((size_t)kb * NJ16 + bj0 + blk) * 64 + ql) * 8,
                        &lds[buf][1][(size_t)q * 8]);
        }
    };

    // prologue: tile 0
    issueA(0);
    stageB(0, 0);
    writeA(0);

    int cur = 0;
    for (int kb = 0; kb < NBK; ++kb) {
        __syncthreads();   // drains B gload (vmcnt) + A ds_write (lgkm) of tile kb
        if (kb + 1 < NBK) {
            issueA(kb + 1);             // f32 loads first (oldest in vmcnt queue)
            stageB(kb + 1, cur ^ 1);
        }

        f16x8 bf[4];
#pragma unroll
        for (int nb = 0; nb < 4; ++nb)
            bf[nb] = *reinterpret_cast<const f16x8*>(&lds[cur][1][((wc * 4 + nb) * 64 + l) * 8]);

        __builtin_amdgcn_s_setprio(1);
#pragma unroll
        for (int mb = 0; mb < 4; ++mb) {
            f16x8 af = *reinterpret_cast<const f16x8*>(&lds[cur][0][((wr * 4 + mb) * 64 + l) * 8]);
#pragma unroll
            for (int nb = 0; nb < 4; ++nb)
                acc[mb][nb] = __builtin_amdgcn_mfma_f32_16x16x32_f16(af, bf[nb], acc[mb][nb], 0, 0, 0);
        }
        __builtin_amdgcn_s_setprio(0);

        if (kb + 1 < NBK) writeA(cur ^ 1);   // rA vmcnt-wait sat under MFMA
        cur ^= 1;
    }

    const int mrow0 = bmIdx * 128 + wr * 64;
    const int jcol0 = bjIdx * 128 + wc * 64;
#pragma unroll
    for (int mb = 0; mb < 4; ++mb)
#pragma unroll
        for (int nb = 0; nb < 4; ++nb) {
            const int j = jcol0 + nb * 16 + (l & 15);
            const int mbase = mrow0 + mb * 16 + (l >> 4) * 4;
#pragma unroll
            for (int r = 0; r < 4; ++r)
                Y[(size_t)(mbase + r) * NJ + j] = (half_t)acc[mb][nb][r];
        }
}

// ---------------- single-pass f16 MFMA GEMM (pre-blocked A), 2-phase dbuf ----------------
template <int NBK>   // conv2: 8
__global__ __launch_bounds__(256, 4) void gemm_f16_kernel(
    const half_t* __restrict__ Ap, const half_t* __restrict__ Bp,
    half_t* __restrict__ Y) {
    __shared__ __align__(16) half_t lds[2][2][4096];   // 32 KB
    const int tid = threadIdx.x;
    const int l = tid & 63;
    const int wv = tid >> 6;
    const int wr = wv >> 1, wc = wv & 1;

    const int d = blockIdx.x;                  // 0..767
    const int work = (d & 7) * 96 + (d >> 3);
    const int bjIdx = work % 6;
    const int bmIdx = work / 6;
    const int bm0 = bmIdx * 8;
    const int bj0 = bjIdx * 8;

    f32x4 acc[4][4] = {};

    auto stage = [&](int kb, int buf) {
#pragma unroll
        for (int s = 0; s < 2; ++s) {
            const int q = tid + 256 * s;
            const int blk = q >> 6;
            const int ql = q & 63;
            gload_lds16(Ap + (((size_t)(bm0 + blk) * NBK + kb) * 64 + ql) * 8,
                        &lds[buf][0][(size_t)q * 8]);
            gload_lds16(Bp + (((size_t)kb * NJ16 + bj0 + blk) * 64 + ql) * 8,
                        &lds[buf][1][(size_t)q * 8]);
        }
    };

    stage(0, 0);
    int cur = 0;
    for (int kb = 0; kb < NBK; ++kb) {
        __syncthreads();
        if (kb + 1 < NBK) stage(kb + 1, cur ^ 1);

        f16x8 bf[4];
#pragma unroll
        for (int nb = 0; nb < 4; ++nb)
            bf[nb] = *reinterpret_cast<const f16x8*>(&lds[cur][1][((wc * 4 + nb) * 64 + l) * 8]);

        __builtin_amdgcn_s_setprio(1);
#pragma unroll
        for (int mb = 0; mb < 4; ++mb) {
            f16x8 af = *reinterpret_cast<const f16x8*>(&lds[cur][0][((wr * 4 + mb) * 64 + l) * 8]);
#pragma unroll
            for (int nb = 0; nb < 4; ++nb)
                acc[mb][nb] = __builtin_amdgcn_mfma_f32_16x16x32_f16(af, bf[nb], acc[mb][nb], 0, 0, 0);
        }
        __builtin_amdgcn_s_setprio(0);
        cur ^= 1;
    }

    const int mrow0 = bmIdx * 128 + wr * 64;
    const int jcol0 = bjIdx * 128 + wc * 64;
#pragma unroll
    for (int mb = 0; mb < 4; ++mb)
#pragma unroll
        for (int nb = 0; nb < 4; ++nb) {
            const int j = jcol0 + nb * 16 + (l & 15);
            const int mbase = mrow0 + mb * 16 + (l >> 4) * 4;
#pragma unroll
            for (int r = 0; r < 4; ++r)
                Y[(size_t)(mbase + r) * NJ + j] = (half_t)acc[mb][nb][r];
        }
}

// ---------------- combine(3-tap) + bias + relu + LN + *mask -> fragment-blocked A2 (f16) ----
// wave-per-row: 4 waves x 4 rows, full-wave shfl_xor reductions, single barrier.
__global__ __launch_bounds__(256) void ln1_kernel(
    const half_t* __restrict__ Y1, const float* __restrict__ cb,
    const float* __restrict__ g, const float* __restrict__ b,
    const unsigned char* __restrict__ mraw,
    half_t* __restrict__ A2p) {
    __shared__ float xs[16][260];
    const int bm = blockIdx.x;
    const int wvv = threadIdx.x >> 6;
    const int lane = threadIdx.x & 63;
    const int h0 = lane * 4;
    const float4 cb4 = *reinterpret_cast<const float4*>(&cb[h0]);
    const float4 g4  = *reinterpret_cast<const float4*>(&g[h0]);
    const float4 b4  = *reinterpret_cast<const float4*>(&b[h0]);
#pragma unroll
    for (int i = 0; i < 4; ++i) {
        const int r = wvv * 4 + i;
        const int t = bm * 16 + r;
        f16x4 c4 = *reinterpret_cast<const f16x4*>(&Y1[(size_t)t * NJ + 256 + h0]);
        float v[4];
#pragma unroll
        for (int j = 0; j < 4; ++j) v[j] = (float)c4[j];
        if ((t & (T_ - 1)) != 0) {
            f16x4 l4 = *reinterpret_cast<const f16x4*>(&Y1[(size_t)(t - 1) * NJ + h0]);
#pragma unroll
            for (int j = 0; j < 4; ++j) v[j] += (float)l4[j];
        }
        if ((t & (T_ - 1)) != T_ - 1) {
            f16x4 r4 = *reinterpret_cast<const f16x4*>(&Y1[(size_t)(t + 1) * NJ + 512 + h0]);
#pragma unroll
            for (int j = 0; j < 4; ++j) v[j] += (float)r4[j];
        }
        v[0] = fmaxf(v[0] + cb4.x, 0.f); v[1] = fmaxf(v[1] + cb4.y, 0.f);
        v[2] = fmaxf(v[2] + cb4.z, 0.f); v[3] = fmaxf(v[3] + cb4.w, 0.f);
        float s  = v[0] + v[1] + v[2] + v[3];
        float ss = v[0]*v[0] + v[1]*v[1] + v[2]*v[2] + v[3]*v[3];
#pragma unroll
        for (int off = 1; off < 64; off <<= 1) {
            s  += __shfl_xor(s, off);
            ss += __shfl_xor(ss, off);
        }
        const float mu  = s * (1.0f / H_);
        const float var = ss * (1.0f / H_) - mu * mu;
        const float inv = 1.0f / sqrtf(var + 1e-5f);
        const float mv = mask_at(mraw, t);
        float4 o;
        o.x = ((v[0] - mu) * inv * g4.x + b4.x) * mv;
        o.y = ((v[1] - mu) * inv * g4.y + b4.y) * mv;
        o.z = ((v[2] - mu) * inv * g4.z + b4.z) * mv;
        o.w = ((v[3] - mu) * inv * g4.w + b4.w) * mv;
        *reinterpret_cast<float4*>(&xs[r][h0]) = o;
    }
    __syncthreads();
#pragma unroll
    for (int s2 = 0; s2 < 2; ++s2) {
        const int q = threadIdx.x + 256 * s2;   // 0..511
        const int l = q & 63;
        const int bk = q >> 6;                  // 0..7
        const int rr = l & 15;
        const int hh = bk * 32 + ((l >> 4) * 8);
        f16x8 h8;
#pragma unroll
        for (int jj = 0; jj < 8; ++jj) h8[jj] = (half_t)xs[rr][hh + jj];
        *reinterpret_cast<f16x8*>(A2p + ((size_t)(bm * 8 + bk) * 64 + l) * 8) = h8;
    }
}

// ---------------- combine + bias + relu + LN + proj + duration (wave-per-row) ----------------
__global__ __launch_bounds__(256) void ln2_proj_dur_kernel(
    const half_t* __restrict__ Y2, const float* __restrict__ cb,
    const float* __restrict__ g, const float* __restrict__ b,
    const float* __restrict__ pw, const float* __restrict__ pb,
    const unsigned char* __restrict__ mraw, int* __restrict__ dur) {
    const int t = blockIdx.x * 4 + (threadIdx.x >> 6);
    const int lane = threadIdx.x & 63;
    const int h0 = lane * 4;

    f16x4 c4 = *reinterpret_cast<const f16x4*>(&Y2[(size_t)t * NJ + 256 + h0]);
    float v[4];
#pragma unroll
    for (int i = 0; i < 4; ++i) v[i] = (float)c4[i];
    if ((t & (T_ - 1)) != 0) {
        f16x4 l4 = *reinterpret_cast<const f16x4*>(&Y2[(size_t)(t - 1) * NJ + h0]);
#pragma unroll
        for (int i = 0; i < 4; ++i) v[i] += (float)l4[i];
    }
    if ((t & (T_ - 1)) != T_ - 1) {
        f16x4 r4 = *reinterpret_cast<const f16x4*>(&Y2[(size_t)(t + 1) * NJ + 512 + h0]);
#pragma unroll
        for (int i = 0; i < 4; ++i) v[i] += (float)r4[i];
    }
    float4 cb4 = *reinterpret_cast<const float4*>(&cb[h0]);
    v[0] = fmaxf(v[0] + cb4.x, 0.f); v[1] = fmaxf(v[1] + cb4.y, 0.f);
    v[2] = fmaxf(v[2] + cb4.z, 0.f); v[3] = fmaxf(v[3] + cb4.w, 0.f);

    float s = v[0] + v[1] + v[2] + v[3];
    float ss = v[0]*v[0] + v[1]*v[1] + v[2]*v[2] + v[3]*v[3];
#pragma unroll
    for (int off = 1; off < 64; off <<= 1) {
        s  += __shfl_xor(s, off);
        ss += __shfl_xor(ss, off);
    }
    const float mu  = s * (1.0f / H_);
    const float var = ss * (1.0f / H_) - mu * mu;
    const float inv = 1.0f / sqrtf(var + 1e-5f);

    float4 g4 = *reinterpret_cast<const float4*>(&g[h0]);
    float4 b4 = *reinterpret_cast<const float4*>(&b[h0]);
    float4 p4 = *reinterpret_cast<const float4*>(&pw[h0]);
    float c = ((v[0]-mu)*inv*g4.x + b4.x) * p4.x
            + ((v[1]-mu)*inv*g4.y + b4.y) * p4.y
            + ((v[2]-mu)*inv*g4.z + b4.z) * p4.z
            + ((v[3]-mu)*inv*g4.w + b4.w) * p4.w;
#pragma unroll
    for (int off = 1; off < 64; off <<= 1) c += __shfl_xor(c, off);

    if (lane == 0) {
        const float ld = c + pb[0];
        const float dv = rintf(expf(ld) - 1.0f);
        int di = (int)dv;
        if (di < 0) di = 0;
        if (mask_at(mraw, t) == 0.0f) di = 0;
        dur[t] = di;
    }
}

// ---------------- per-sequence inclusive cumsum (T=1024) ----------------
__global__ __launch_bounds__(1024) void cumsum_kernel(
    const int* __restrict__ dur, int* __restrict__ cum,
    float* __restrict__ seq_lens_out) {
    __shared__ int s[1024];
    const int n = blockIdx.x, t = threadIdx.x;
    s[t] = dur[n * T_ + t];
    __syncthreads();
    for (int off = 1; off < 1024; off <<= 1) {
        int v = (t >= off) ? s[t - off] : 0;
        __syncthreads();
        s[t] += v;
        __syncthreads();
    }
    cum[n * T_ + t] = s[t];
    if (t == T_ - 1) seq_lens_out[n] = (float)s[t];
}

// ---------------- length-regulator upsample (wave-per-position, nt stores) ----------------
__global__ __launch_bounds__(256) void upsample_kernel(
    const float* __restrict__ seqs, const int* __restrict__ cum,
    float* __restrict__ out) {
    const int wid = blockIdx.x * 4 + (threadIdx.x >> 6);   // n*MAXOUT + p
    const int n = wid >> 12;
    const int p = wid & (MAXOUT - 1);
    const int lane = threadIdx.x & 63;
    const int* c = cum + n * T_;
    const int slen = c[T_ - 1];
    int lo = 0, hi = T_;
    while (lo < hi) {                 // upper_bound: first idx with c[idx] > p (wave-uniform)
        int mid = (lo + hi) >> 1;
        if (c[mid] <= p) lo = mid + 1; else hi = mid;
    }
    const int idx = (lo < T_ - 1) ? lo : (T_ - 1);
    const bool valid = (p < slen);
    const f32x4* src = reinterpret_cast<const f32x4*>(seqs + ((size_t)(n * T_ + idx) * E_));
    f32x4* dst = reinterpret_cast<f32x4*>(out + (size_t)wid * E_);
#pragma unroll
    for (int i = 0; i < 4; ++i) {
        f32x4 v = {0.f, 0.f, 0.f, 0.f};
        if (valid) v = src[lane + 64 * i];
        __builtin_nontemporal_store(v, &dst[lane + 64 * i]);
    }
}

// ---------------- launch ----------------
extern "C" void kernel_launch(void* const* d_in, const int* in_sizes, int n_in,
                              void* d_out, int out_size, void* d_ws, size_t ws_size,
                              hipStream_t stream) {
    const float* seqs = (const float*)d_in[0];
    const float* w1   = (const float*)d_in[1];
    const float* b1   = (const float*)d_in[2];
    const float* g1   = (const float*)d_in[3];
    const float* bb1  = (const float*)d_in[4];
    const float* w2   = (const float*)d_in[5];
    const float* b2   = (const float*)d_in[6];
    const float* g2   = (const float*)d_in[7];
    const float* bb2  = (const float*)d_in[8];
    const float* pw   = (const float*)d_in[9];
    const float* pb   = (const float*)d_in[10];
    const unsigned char* mraw = (const unsigned char*)d_in[11];

    char* wsb = (char*)d_ws;
    half_t* B1p = (half_t*)(wsb + B1P_OFF);
    half_t* B2p = (half_t*)(wsb + B2P_OFF);
    int* dur = (int*)(wsb + DUR_OFF);
    int* cum = (int*)(wsb + CUM_OFF);

    char* outb = (char*)d_out;
    half_t* Y1  = (half_t*)(outb + Y1_OFF);
    half_t* Y2  = (half_t*)(outb + Y2_OFF);
    half_t* A2p = (half_t*)(outb + A2P_OFF);

    float* out      = (float*)d_out;
    float* slen_out = out + (size_t)N_ * MAXOUT * E_;

    prep_w_kernel<<<480, 256, 0, stream>>>(w1, w2, B1p, B2p);
    gemm1_fused_kernel<<<768, 256, 0, stream>>>(seqs, mraw, B1p, Y1);
    ln1_kernel<<<M_ / 16, 256, 0, stream>>>(Y1, b1, g1, bb1, mraw, A2p);
    gemm_f16_kernel<8><<<768, 256, 0, stream>>>(A2p, B2p, Y2);
    ln2_proj_dur_kernel<<<M_ / 4, 256, 0, stream>>>(Y2, b2, g2, bb2, pw, pb, mraw, dur);
    cumsum_kernel<<<N_, 1024, 0, stream>>>(dur, cum, slen_out);
    upsample_kernel<<<(N_ * MAXOUT) / 4, 256, 0, stream>>>(seqs, cum, out);
}

// Round 8
// 131.133 us; speedup vs baseline: 1.1867x; 1.1867x over previous
//
#include <hip/hip_runtime.h>

#define N_ 16
#define T_ 1024
#define E_ 1024
#define H_ 256
#define MAXOUT 4096
#define M_ (N_ * T_)          // 16384 rows
#define NJ 768                // 3*H_ GEMM output cols
#define NJ16 48               // NJ/16

typedef _Float16 half_t;
typedef __attribute__((ext_vector_type(8))) _Float16 f16x8;
typedef __attribute__((ext_vector_type(4))) _Float16 f16x4;
typedef __attribute__((ext_vector_type(4))) float f32x4;

// ---------------- d_out scratch layout (bytes) ----------------
// upsample (last kernel) rewrites the entire main output region.
constexpr size_t Y1_OFF  = 0;                       // 16384*768*2  = 25165824
constexpr size_t Y2_OFF  = 25165824;                // + 25165824
constexpr size_t A0P_OFF = 50331648;                // 16384*1024*2 = 33554432
constexpr size_t A2P_OFF = 83886080;                // 16384*256*2  = 8388608 -> ends 92274688

// ---------------- d_ws layout (bytes) ----------------
constexpr size_t B1P_OFF  = 0;            // 786432*2 = 1572864
constexpr size_t B2P_OFF  = 1572864;      // 196608*2 = 393216
constexpr size_t DUR_OFF  = 1966080;      // 16384*4
constexpr size_t CUM_OFF  = 2031616;      // 16384*4

// mask decode, dtype-robust. padding_mask[0][1] is guaranteed true (lens>=512):
// bool-byte storage -> raw[1]==1; int32/float32 -> raw[1]==0, read 4-byte words.
__device__ __forceinline__ float mask_at(const unsigned char* __restrict__ raw, int i) {
    if (raw[1] == 1) return raw[i] ? 1.0f : 0.0f;
    return reinterpret_cast<const int*>(raw)[i] ? 1.0f : 0.0f;
}

__device__ __forceinline__ void gload_lds16(const void* g, void* l) {
    __builtin_amdgcn_global_load_lds(
        (const __attribute__((address_space(1))) unsigned int*)g,
        (__attribute__((address_space(3))) unsigned int*)l, 16, 0, 0);
}

// ---------------- fused prep: A-convert (blocks 0..1023) | W1 (..1407) | W2 (..1503) ----
// A: seqs*mask -> A0p [bm][bk=32][64][8] f16 fragment-blocked
// W: w[h][e][k] -> B[e][j=k*256+h] blocked [bk][bj=48][64][8] f16
__global__ __launch_bounds__(256) void prep_all_kernel(
    const float* __restrict__ X, const unsigned char* __restrict__ mraw,
    const float* __restrict__ w1, const float* __restrict__ w2,
    half_t* __restrict__ A0p, half_t* __restrict__ B1p, half_t* __restrict__ B2p) {
    const int bid = blockIdx.x;
    if (bid < 1024) {
        const int bm = bid;
        const int l = threadIdx.x & 63;
        const int bk4 = threadIdx.x >> 6;       // 0..3
        const int row = bm * 16 + (l & 15);
        const float mv = mask_at(mraw, row);
        const float* src = X + (size_t)row * E_ + ((l >> 4) * 8);
#pragma unroll
        for (int g = 0; g < 8; ++g) {
            const int bk = g * 4 + bk4;         // 0..31
            float4 v0 = *reinterpret_cast<const float4*>(src + bk * 32);
            float4 v1 = *reinterpret_cast<const float4*>(src + bk * 32 + 4);
            float v[8] = {v0.x, v0.y, v0.z, v0.w, v1.x, v1.y, v1.z, v1.w};
            f16x8 h8;
#pragma unroll
            for (int j = 0; j < 8; ++j) h8[j] = (half_t)(v[j] * mv);
            *reinterpret_cast<f16x8*>(A0p + ((size_t)(bm * 32 + bk) * 64 + l) * 8) = h8;
        }
    } else {
        const bool isW1 = (bid < 1024 + 384);
        const int c = (isW1 ? (bid - 1024) : (bid - 1408)) * 256 + threadIdx.x;
        const int EIN = isW1 ? E_ : H_;
        const float* w = isW1 ? w1 : w2;
        half_t* Bp = isW1 ? B1p : B2p;
        const int l = c & 63;
        const int t = c >> 6;
        const int bj = t % NJ16;
        const int bk = t / NJ16;
        const int j = bj * 16 + (l & 15);
        const int k = j >> 8;           // 0..2
        const int h = j & 255;
        const int e0 = bk * 32 + ((l >> 4) * 8);
        f16x8 h8;
#pragma unroll
        for (int jj = 0; jj < 8; ++jj)
            h8[jj] = (half_t)w[((size_t)h * EIN + e0 + jj) * 3 + k];
        *reinterpret_cast<f16x8*>(Bp + (size_t)c * 8) = h8;
    }
}

// ---------------- single-pass f16 MFMA GEMM, 2-phase dbuf, early prefetch ----------------
// Y[M][768] (f16) = A[M][K] * B[K][768];  K = NBK*32
// 1-D grid of 768 blocks; T1 XCD-chunked swizzle (768%8==0) + j-inner decode:
// the 6 blocks sharing an A-panel are dispatch-adjacent on the SAME XCD -> A L2-reuse.
template <int NBK>   // conv1: 32, conv2: 8
__global__ __launch_bounds__(256, 4) void gemm_f16_kernel(
    const half_t* __restrict__ Ap, const half_t* __restrict__ Bp,
    half_t* __restrict__ Y) {
    __shared__ __align__(16) half_t lds[2][2][4096];   // [buf][A,B][128x32 tile] = 32 KB
    const int tid = threadIdx.x;
    const int l = tid & 63;
    const int wv = tid >> 6;
    const int wr = wv >> 1, wc = wv & 1;

    const int d = blockIdx.x;                  // dispatch id, 0..767
    const int work = (d & 7) * 96 + (d >> 3);  // XCD-chunked: XCD (d%8) gets contiguous 96 works
    const int bjIdx = work % 6;                // j-inner: A-panel sharers adjacent
    const int bmIdx = work / 6;
    const int bm0 = bmIdx * 8;     // m-block base (rows of 16)
    const int bj0 = bjIdx * 8;     // j-block base (cols of 16)

    f32x4 acc[4][4] = {};

    auto stage = [&](int kb, int buf) {
#pragma unroll
        for (int s = 0; s < 2; ++s) {
            const int q = tid + 256 * s;          // 0..511 chunk in tile
            const int blk = q >> 6;
            const int ql = q & 63;
            gload_lds16(Ap + (((size_t)(bm0 + blk) * NBK + kb) * 64 + ql) * 8,
                        &lds[buf][0][(size_t)q * 8]);
            gload_lds16(Bp + (((size_t)kb * NJ16 + bj0 + blk) * 64 + ql) * 8,
                        &lds[buf][1][(size_t)q * 8]);
        }
    };

    stage(0, 0);
    int cur = 0;
    for (int kb = 0; kb < NBK; ++kb) {
        __syncthreads();   // drains stage(kb) (vmcnt) + prior-tile reads (lgkm)
        // issue next-tile prefetch FIRST so ds_reads + MFMA cover its latency
        if (kb + 1 < NBK) stage(kb + 1, cur ^ 1);

        f16x8 bf[4];
#pragma unroll
        for (int nb = 0; nb < 4; ++nb)
            bf[nb] = *reinterpret_cast<const f16x8*>(&lds[cur][1][((wc * 4 + nb) * 64 + l) * 8]);

        __builtin_amdgcn_s_setprio(1);
#pragma unroll
        for (int mb = 0; mb < 4; ++mb) {
            f16x8 af = *reinterpret_cast<const f16x8*>(&lds[cur][0][((wr * 4 + mb) * 64 + l) * 8]);
#pragma unroll
            for (int nb = 0; nb < 4; ++nb)
                acc[mb][nb] = __builtin_amdgcn_mfma_f32_16x16x32_f16(af, bf[nb], acc[mb][nb], 0, 0, 0);
        }
        __builtin_amdgcn_s_setprio(0);
        cur ^= 1;
    }

    const int mrow0 = bmIdx * 128 + wr * 64;
    const int jcol0 = bjIdx * 128 + wc * 64;
#pragma unroll
    for (int mb = 0; mb < 4; ++mb)
#pragma unroll
        for (int nb = 0; nb < 4; ++nb) {
            const int j = jcol0 + nb * 16 + (l & 15);
            const int mbase = mrow0 + mb * 16 + (l >> 4) * 4;
#pragma unroll
            for (int r = 0; r < 4; ++r)
                Y[(size_t)(mbase + r) * NJ + j] = (half_t)acc[mb][nb][r];
        }
}

// ---------------- combine(3-tap) + bias + relu + LN + *mask -> fragment-blocked A2 (f16) ----
// 32-lane row-groups: each wave handles 2 rows/iter with f16x8 (16B) loads,
// 5-step shfl_xor reduction within the 32-group. Repack phase unchanged.
__global__ __launch_bounds__(256) void ln1_kernel(
    const half_t* __restrict__ Y1, const float* __restrict__ cb,
    const float* __restrict__ g, const float* __restrict__ b,
    const unsigned char* __restrict__ mraw,
    half_t* __restrict__ A2p) {
    __shared__ float xs[16][260];
    const int bm = blockIdx.x;
    const int wvv = threadIdx.x >> 6;      // 0..3
    const int lane = threadIdx.x & 63;
    const int half32 = lane >> 5;          // 0/1: which row of the pair
    const int l32 = lane & 31;
    const int h0 = l32 * 8;                // 8 cols per lane
    float cbv[8], gv[8], bv[8];
    *reinterpret_cast<float4*>(&cbv[0]) = *reinterpret_cast<const float4*>(&cb[h0]);
    *reinterpret_cast<float4*>(&cbv[4]) = *reinterpret_cast<const float4*>(&cb[h0 + 4]);
    *reinterpret_cast<float4*>(&gv[0])  = *reinterpret_cast<const float4*>(&g[h0]);
    *reinterpret_cast<float4*>(&gv[4])  = *reinterpret_cast<const float4*>(&g[h0 + 4]);
    *reinterpret_cast<float4*>(&bv[0])  = *reinterpret_cast<const float4*>(&b[h0]);
    *reinterpret_cast<float4*>(&bv[4])  = *reinterpret_cast<const float4*>(&b[h0 + 4]);
#pragma unroll
    for (int i = 0; i < 2; ++i) {
        const int r = wvv * 2 + half32 + i * 8;   // rows 0..15
        const int t = bm * 16 + r;
        f16x8 c8 = *reinterpret_cast<const f16x8*>(&Y1[(size_t)t * NJ + 256 + h0]);
        float v[8];
#pragma unroll
        for (int j = 0; j < 8; ++j) v[j] = (float)c8[j];
        if ((t & (T_ - 1)) != 0) {
            f16x8 l8 = *reinterpret_cast<const f16x8*>(&Y1[(size_t)(t - 1) * NJ + h0]);
#pragma unroll
            for (int j = 0; j < 8; ++j) v[j] += (float)l8[j];
        }
        if ((t & (T_ - 1)) != T_ - 1) {
            f16x8 r8 = *reinterpret_cast<const f16x8*>(&Y1[(size_t)(t + 1) * NJ + 512 + h0]);
#pragma unroll
            for (int j = 0; j < 8; ++j) v[j] += (float)r8[j];
        }
        float s = 0.f, ss = 0.f;
#pragma unroll
        for (int j = 0; j < 8; ++j) {
            v[j] = fmaxf(v[j] + cbv[j], 0.f);
            s += v[j];
            ss += v[j] * v[j];
        }
#pragma unroll
        for (int off = 1; off < 32; off <<= 1) {
            s  += __shfl_xor(s, off);
            ss += __shfl_xor(ss, off);
        }
        const float mu  = s * (1.0f / H_);
        const float var = ss * (1.0f / H_) - mu * mu;
        const float inv = 1.0f / sqrtf(var + 1e-5f);
        const float mv = mask_at(mraw, t);
        float o[8];
#pragma unroll
        for (int j = 0; j < 8; ++j) o[j] = ((v[j] - mu) * inv * gv[j] + bv[j]) * mv;
        *reinterpret_cast<float4*>(&xs[r][h0])     = *reinterpret_cast<float4*>(&o[0]);
        *reinterpret_cast<float4*>(&xs[r][h0 + 4]) = *reinterpret_cast<float4*>(&o[4]);
    }
    __syncthreads();
#pragma unroll
    for (int s2 = 0; s2 < 2; ++s2) {
        const int q = threadIdx.x + 256 * s2;   // 0..511
        const int l = q & 63;
        const int bk = q >> 6;                  // 0..7
        const int rr = l & 15;
        const int hh = bk * 32 + ((l >> 4) * 8);
        f16x8 h8;
#pragma unroll
        for (int jj = 0; jj < 8; ++jj) h8[jj] = (half_t)xs[rr][hh + jj];
        *reinterpret_cast<f16x8*>(A2p + ((size_t)(bm * 8 + bk) * 64 + l) * 8) = h8;
    }
}

// ---------------- combine + bias + relu + LN + proj + duration ----------------
// 32-lane row-groups, f16x8 loads, 2 rows/wave, 8 rows/block.
__global__ __launch_bounds__(256) void ln2_proj_dur_kernel(
    const half_t* __restrict__ Y2, const float* __restrict__ cb,
    const float* __restrict__ g, const float* __restrict__ b,
    const float* __restrict__ pw, const float* __restrict__ pb,
    const unsigned char* __restrict__ mraw, int* __restrict__ dur) {
    const int lane = threadIdx.x & 63;
    const int l32 = lane & 31;
    const int t = blockIdx.x * 8 + (threadIdx.x >> 6) * 2 + (lane >> 5);
    const int h0 = l32 * 8;

    f16x8 c8 = *reinterpret_cast<const f16x8*>(&Y2[(size_t)t * NJ + 256 + h0]);
    float v[8];
#pragma unroll
    for (int j = 0; j < 8; ++j) v[j] = (float)c8[j];
    if ((t & (T_ - 1)) != 0) {
        f16x8 l8 = *reinterpret_cast<const f16x8*>(&Y2[(size_t)(t - 1) * NJ + h0]);
#pragma unroll
        for (int j = 0; j < 8; ++j) v[j] += (float)l8[j];
    }
    if ((t & (T_ - 1)) != T_ - 1) {
        f16x8 r8 = *reinterpret_cast<const f16x8*>(&Y2[(size_t)(t + 1) * NJ + 512 + h0]);
#pragma unroll
        for (int j = 0; j < 8; ++j) v[j] += (float)r8[j];
    }
    float cbv[8], gv[8], bv[8], pv[8];
    *reinterpret_cast<float4*>(&cbv[0]) = *reinterpret_cast<const float4*>(&cb[h0]);
    *reinterpret_cast<float4*>(&cbv[4]) = *reinterpret_cast<const float4*>(&cb[h0 + 4]);
    *reinterpret_cast<float4*>(&gv[0])  = *reinterpret_cast<const float4*>(&g[h0]);
    *reinterpret_cast<float4*>(&gv[4])  = *reinterpret_cast<const float4*>(&g[h0 + 4]);
    *reinterpret_cast<float4*>(&bv[0])  = *reinterpret_cast<const float4*>(&b[h0]);
    *reinterpret_cast<float4*>(&bv[4])  = *reinterpret_cast<const float4*>(&b[h0 + 4]);
    *reinterpret_cast<float4*>(&pv[0])  = *reinterpret_cast<const float4*>(&pw[h0]);
    *reinterpret_cast<float4*>(&pv[4])  = *reinterpret_cast<const float4*>(&pw[h0 + 4]);

    float s = 0.f, ss = 0.f;
#pragma unroll
    for (int j = 0; j < 8; ++j) {
        v[j] = fmaxf(v[j] + cbv[j], 0.f);
        s += v[j];
        ss += v[j] * v[j];
    }
#pragma unroll
    for (int off = 1; off < 32; off <<= 1) {
        s  += __shfl_xor(s, off);
        ss += __shfl_xor(ss, off);
    }
    const float mu  = s * (1.0f / H_);
    const float var = ss * (1.0f / H_) - mu * mu;
    const float inv = 1.0f / sqrtf(var + 1e-5f);

    float c = 0.f;
#pragma unroll
    for (int j = 0; j < 8; ++j)
        c += ((v[j] - mu) * inv * gv[j] + bv[j]) * pv[j];
#pragma unroll
    for (int off = 1; off < 32; off <<= 1) c += __shfl_xor(c, off);

    if (l32 == 0) {
        const float ld = c + pb[0];
        const float dv = rintf(expf(ld) - 1.0f);
        int di = (int)dv;
        if (di < 0) di = 0;
        if (mask_at(mraw, t) == 0.0f) di = 0;
        dur[t] = di;
    }
}

// ---------------- per-sequence inclusive cumsum (T=1024) ----------------
__global__ __launch_bounds__(1024) void cumsum_kernel(
    const int* __restrict__ dur, int* __restrict__ cum,
    float* __restrict__ seq_lens_out) {
    __shared__ int s[1024];
    const int n = blockIdx.x, t = threadIdx.x;
    s[t] = dur[n * T_ + t];
    __syncthreads();
    for (int off = 1; off < 1024; off <<= 1) {
        int v = (t >= off) ? s[t - off] : 0;
        __syncthreads();
        s[t] += v;
        __syncthreads();
    }
    cum[n * T_ + t] = s[t];
    if (t == T_ - 1) seq_lens_out[n] = (float)s[t];
}

// ---------------- length-regulator upsample (wave-per-position, nt stores) ----------------
__global__ __launch_bounds__(256) void upsample_kernel(
    const float* __restrict__ seqs, const int* __restrict__ cum,
    float* __restrict__ out) {
    const int wid = blockIdx.x * 4 + (threadIdx.x >> 6);   // n*MAXOUT + p
    const int n = wid >> 12;
    const int p = wid & (MAXOUT - 1);
    const int lane = threadIdx.x & 63;
    const int* c = cum + n * T_;
    const int slen = c[T_ - 1];
    int lo = 0, hi = T_;
    while (lo < hi) {                 // upper_bound: first idx with c[idx] > p (wave-uniform)
        int mid = (lo + hi) >> 1;
        if (c[mid] <= p) lo = mid + 1; else hi = mid;
    }
    const int idx = (lo < T_ - 1) ? lo : (T_ - 1);
    const bool valid = (p < slen);
    const f32x4* src = reinterpret_cast<const f32x4*>(seqs + ((size_t)(n * T_ + idx) * E_));
    f32x4* dst = reinterpret_cast<f32x4*>(out + (size_t)wid * E_);
#pragma unroll
    for (int i = 0; i < 4; ++i) {
        f32x4 v = {0.f, 0.f, 0.f, 0.f};
        if (valid) v = src[lane + 64 * i];
        __builtin_nontemporal_store(v, &dst[lane + 64 * i]);
    }
}

// ---------------- launch ----------------
extern "C" void kernel_launch(void* const* d_in, const int* in_sizes, int n_in,
                              void* d_out, int out_size, void* d_ws, size_t ws_size,
                              hipStream_t stream) {
    const float* seqs = (const float*)d_in[0];
    const float* w1   = (const float*)d_in[1];
    const float* b1   = (const float*)d_in[2];
    const float* g1   = (const float*)d_in[3];
    const float* bb1  = (const float*)d_in[4];
    const float* w2   = (const float*)d_in[5];
    const float* b2   = (const float*)d_in[6];
    const float* g2   = (const float*)d_in[7];
    const float* bb2  = (const float*)d_in[8];
    const float* pw   = (const float*)d_in[9];
    const float* pb   = (const float*)d_in[10];
    const unsigned char* mraw = (const unsigned char*)d_in[11];

    char* wsb = (char*)d_ws;
    half_t* B1p = (half_t*)(wsb + B1P_OFF);
    half_t* B2p = (half_t*)(wsb + B2P_OFF);
    int* dur = (int*)(wsb + DUR_OFF);
    int* cum = (int*)(wsb + CUM_OFF);

    char* outb = (char*)d_out;
    half_t* Y1  = (half_t*)(outb + Y1_OFF);
    half_t* Y2  = (half_t*)(outb + Y2_OFF);
    half_t* A0p = (half_t*)(outb + A0P_OFF);
    half_t* A2p = (half_t*)(outb + A2P_OFF);

    float* out      = (float*)d_out;
    float* slen_out = out + (size_t)N_ * MAXOUT * E_;

    // fused: A-convert (1024 blocks) | W1 (384) | W2 (96)
    prep_all_kernel<<<1504, 256, 0, stream>>>(seqs, mraw, w1, w2, A0p, B1p, B2p);
    gemm_f16_kernel<32><<<768, 256, 0, stream>>>(A0p, B1p, Y1);
    ln1_kernel<<<M_ / 16, 256, 0, stream>>>(Y1, b1, g1, bb1, mraw, A2p);
    gemm_f16_kernel<8><<<768, 256, 0, stream>>>(A2p, B2p, Y2);
    ln2_proj_dur_kernel<<<M_ / 8, 256, 0, stream>>>(Y2, b2, g2, bb2, pw, pb, mraw, dur);
    cumsum_kernel<<<N_, 1024, 0, stream>>>(dur, cum, slen_out);
    upsample_kernel<<<(N_ * MAXOUT) / 4, 256, 0, stream>>>(seqs, cum, out);
}